// Round 2
// baseline (1527.564 us; speedup 1.0000x reference)
//
#include <hip/hip_runtime.h>
#include <cstdint>
#include <cstddef>

#define T_DIM 4096
#define H_DIM 4096
#define I_DIM 11008

typedef int v4i  __attribute__((ext_vector_type(4)));
typedef int v16i __attribute__((ext_vector_type(16)));

// ---------------------------------------------------------------------------
// async global->LDS copy, 16B per lane (global_load_lds_dwordx4)
// ---------------------------------------------------------------------------
__device__ __forceinline__ void async_copy16(const void* g, void* l) {
  __builtin_amdgcn_global_load_lds(
      (const __attribute__((address_space(1))) void*)g,
      (__attribute__((address_space(3))) void*)l, 16, 0, 0);
}

// Stage a 128x64 int8 tile (row-major, leading dim ld) into LDS (8 KB).
// LDS: row r at [r*64, r*64+64), 4 chunks of 16B. XOR swizzle applied on the
// GLOBAL source address (global_load_lds dest is wave-uniform base + lane*16):
// physical chunk p holds logical chunk p ^ ((r>>1)&3).
__device__ __forceinline__ void stage_tile(const int8_t* src, size_t ld,
                                           char* ldsbase, int wave, int lane) {
#pragma unroll
  for (int q = 0; q < 2; ++q) {
    int seg = q * 4 + wave;            // 0..7, 16 rows per segment
    int r = seg * 16 + (lane >> 2);    // tile-local row 0..127
    int p = lane & 3;                  // physical 16B chunk
    int c = p ^ ((r >> 1) & 3);        // logical k chunk
    const int8_t* g = src + (size_t)r * ld + (size_t)c * 16;
    char* lp = ldsbase + seg * 1024;   // wave-uniform; HW adds lane*16
    async_copy16((const void*)g, (void*)lp);
  }
}

// 32x32x32 i8 A/B fragment from swizzled tile.
// lane holds row rowbase+(lane&31), 16B of k at chunk kc2 + (lane>>5).
// (k-permutation identical for A and B -> cancels in the dot product.)
__device__ __forceinline__ v4i frag32(const char* ldsbase, int rowbase,
                                      int kc2, int lane) {
  int r = rowbase + (lane & 31);
  int c = (kc2 + (lane >> 5)) ^ ((r >> 1) & 3);
  return *(const v4i*)(ldsbase + r * 64 + c * 16);
}

// ---------------------------------------------------------------------------
// int32 -> int8 pack, 16 elements/thread (16B stores)
// ---------------------------------------------------------------------------
__global__ void pack_i8(const int4* __restrict__ src, v4i* __restrict__ dst, int n16) {
  int stride = gridDim.x * blockDim.x;
  for (int i = blockIdx.x * blockDim.x + threadIdx.x; i < n16; i += stride) {
    int4 a = src[4 * i + 0], b = src[4 * i + 1];
    int4 c = src[4 * i + 2], d = src[4 * i + 3];
    v4i o;
    o[0] = (a.x & 255) | ((a.y & 255) << 8) | ((a.z & 255) << 16) | (a.w << 24);
    o[1] = (b.x & 255) | ((b.y & 255) << 8) | ((b.z & 255) << 16) | (b.w << 24);
    o[2] = (c.x & 255) | ((c.y & 255) << 8) | ((c.z & 255) << 16) | (c.w << 24);
    o[3] = (d.x & 255) | ((d.y & 255) << 8) | ((d.z & 255) << 16) | (d.w << 24);
    dst[i] = o;
  }
}

__global__ void zero_u32(unsigned* __restrict__ p, int n) {
  int i = blockIdx.x * blockDim.x + threadIdx.x;
  if (i < n) p[i] = 0u;
}

// ---------------------------------------------------------------------------
// GEMM1 fused: gate/up in one block (shared A tile), silu(g)*u epilogue,
// fp32 y store + per-row absmax (shfl + atomicMax on float bits).
// 128x(128g+128u) tile, BK=64, mfma_i32_32x32x32_i8, double-buffered LDS,
// ONE barrier per K-iteration (staging of k+1 overlaps compute of k).
// ---------------------------------------------------------------------------
__global__ __launch_bounds__(256, 2)
void gemm1_silu(const int8_t* __restrict__ x8,
                const int8_t* __restrict__ wgu8,
                const float* __restrict__ x_scale,
                const float* __restrict__ s_wgu,
                float* __restrict__ y,
                unsigned* __restrict__ rowmax) {
  __shared__ __align__(16) char lds[49152];   // 2 bufs x (A 8K + Bg 8K + Bu 8K)

  const int tid = threadIdx.x;
  const int wave = tid >> 6, lane = tid & 63;
  const int wm = wave >> 1, wn = wave & 1;   // 2x2 waves, 64x64 each
  const int m0 = blockIdx.y * 128;
  const int n0 = blockIdx.x * 128;

  v16i vzero;
#pragma unroll
  for (int e = 0; e < 16; e++) vzero[e] = 0;
  v16i accg[2][2], accu[2][2];
#pragma unroll
  for (int i = 0; i < 2; i++)
#pragma unroll
    for (int j = 0; j < 2; j++) { accg[i][j] = vzero; accu[i][j] = vzero; }

  const int8_t* Ab  = x8 + (size_t)m0 * H_DIM;
  const int8_t* Bgb = wgu8 + (size_t)n0 * H_DIM;
  const int8_t* Bub = wgu8 + ((size_t)I_DIM + (size_t)n0) * H_DIM;

  // prologue: stage k-block 0 into buffer 0
  stage_tile(Ab, H_DIM, lds, wave, lane);
  stage_tile(Bgb, H_DIM, lds + 8192, wave, lane);
  stage_tile(Bub, H_DIM, lds + 16384, wave, lane);

  int cur = 0;
  for (int k0 = 0; k0 < H_DIM; k0 += 64) {
    __syncthreads();                      // drains staging of buf[cur]
    char* buf = lds + cur * 24576;
    if (k0 + 64 < H_DIM) {                // prefetch next into other buffer
      char* nb = lds + (cur ^ 1) * 24576;
      stage_tile(Ab + k0 + 64, H_DIM, nb, wave, lane);
      stage_tile(Bgb + k0 + 64, H_DIM, nb + 8192, wave, lane);
      stage_tile(Bub + k0 + 64, H_DIM, nb + 16384, wave, lane);
    }
#pragma unroll
    for (int ks = 0; ks < 2; ++ks) {      // two K=32 steps per 64-K tile
      v4i a[2], bg[2], bu[2];
#pragma unroll
      for (int i = 0; i < 2; i++) a[i]  = frag32(buf,         wm * 64 + i * 32, ks * 2, lane);
#pragma unroll
      for (int j = 0; j < 2; j++) bg[j] = frag32(buf + 8192,  wn * 64 + j * 32, ks * 2, lane);
#pragma unroll
      for (int j = 0; j < 2; j++) bu[j] = frag32(buf + 16384, wn * 64 + j * 32, ks * 2, lane);
#pragma unroll
      for (int i = 0; i < 2; i++)
#pragma unroll
        for (int j = 0; j < 2; j++) {
          accg[i][j] = __builtin_amdgcn_mfma_i32_32x32x32_i8(a[i], bg[j], accg[i][j], 0, 0, 0);
          accu[i][j] = __builtin_amdgcn_mfma_i32_32x32x32_i8(a[i], bu[j], accu[i][j], 0, 0, 0);
        }
    }
    cur ^= 1;
  }

  // Epilogue. 32x32 C/D layout: col = lane&31, row = (r&3)+8*(r>>2)+4*(lane>>5).
  const int lc = lane & 31;
  const int lh = lane >> 5;
#pragma unroll
  for (int i = 0; i < 2; i++) {
#pragma unroll
    for (int r = 0; r < 16; r++) {
      const int gr = m0 + wm * 64 + i * 32 + (r & 3) + 8 * (r >> 2) + 4 * lh;
      const float sx = x_scale[gr];
      float vmax = 0.f;
#pragma unroll
      for (int j = 0; j < 2; j++) {
        const int gc = n0 + wn * 64 + j * 32 + lc;
        float g = (float)accg[i][j][r] * sx * s_wgu[gc];
        float u = (float)accu[i][j][r] * sx * s_wgu[I_DIM + gc];
        float yv = (g / (1.f + expf(-g))) * u;   // silu(g) * u
        y[(size_t)gr * I_DIM + gc] = yv;
        vmax = fmaxf(vmax, fabsf(yv));
      }
      // lanes sharing a row are the 32 lanes with the same lane>>5
#pragma unroll
      for (int off = 1; off < 32; off <<= 1)
        vmax = fmaxf(vmax, __shfl_xor(vmax, off, 64));
      if (lc == 0) atomicMax(&rowmax[gr], __float_as_uint(vmax));
    }
  }
}

// ---------------------------------------------------------------------------
// quantize y -> int8, 16 elems/thread. s2 = max(|y|,1e-8)/127, round-half-even
// ---------------------------------------------------------------------------
__global__ void quantize_y(const float* __restrict__ y,
                           const unsigned* __restrict__ rowmax,
                           v4i* __restrict__ yq) {
  size_t i = (size_t)blockIdx.x * blockDim.x + threadIdx.x;
  if (i >= (size_t)T_DIM * I_DIM / 16) return;
  size_t base = i * 16;
  int row = (int)(base / I_DIM);   // I_DIM % 16 == 0: packs never cross rows
  float inv = 127.f / fmaxf(__uint_as_float(rowmax[row]), 1e-8f);
  const float4* p = (const float4*)(y + base);
  v4i o;
#pragma unroll
  for (int q = 0; q < 4; q++) {
    float4 v = p[q];
    int b0 = (int)fminf(127.f, fmaxf(-128.f, rintf(v.x * inv)));
    int b1 = (int)fminf(127.f, fmaxf(-128.f, rintf(v.y * inv)));
    int b2 = (int)fminf(127.f, fmaxf(-128.f, rintf(v.z * inv)));
    int b3 = (int)fminf(127.f, fmaxf(-128.f, rintf(v.w * inv)));
    o[q] = (b0 & 255) | ((b1 & 255) << 8) | ((b2 & 255) << 16) | (b3 << 24);
  }
  yq[i] = o;
}

// ---------------------------------------------------------------------------
// GEMM2: out = (y_q @ w_down^T) * s2[row] * s_w_down[col]
// 128x128 tile, same dbuf single-barrier K-loop, 64 acc regs/wave.
// ---------------------------------------------------------------------------
__global__ __launch_bounds__(256, 3)
void gemm2_scaled(const int8_t* __restrict__ yq8,
                  const int8_t* __restrict__ wd8,
                  const unsigned* __restrict__ rowmax,
                  const float* __restrict__ s_wd,
                  float* __restrict__ out) {
  __shared__ __align__(16) char lds[32768];   // 2 bufs x (A 8K + B 8K)

  const int tid = threadIdx.x;
  const int wave = tid >> 6, lane = tid & 63;
  const int wm = wave >> 1, wn = wave & 1;
  const int m0 = blockIdx.y * 128;
  const int n0 = blockIdx.x * 128;

  v16i vzero;
#pragma unroll
  for (int e = 0; e < 16; e++) vzero[e] = 0;
  v16i acc[2][2];
#pragma unroll
  for (int i = 0; i < 2; i++)
#pragma unroll
    for (int j = 0; j < 2; j++) acc[i][j] = vzero;

  const int8_t* Ab = yq8 + (size_t)m0 * I_DIM;
  const int8_t* Bb = wd8 + (size_t)n0 * I_DIM;

  stage_tile(Ab, I_DIM, lds, wave, lane);
  stage_tile(Bb, I_DIM, lds + 8192, wave, lane);

  int cur = 0;
  for (int k0 = 0; k0 < I_DIM; k0 += 64) {
    __syncthreads();
    char* buf = lds + cur * 16384;
    if (k0 + 64 < I_DIM) {
      char* nb = lds + (cur ^ 1) * 16384;
      stage_tile(Ab + k0 + 64, I_DIM, nb, wave, lane);
      stage_tile(Bb + k0 + 64, I_DIM, nb + 8192, wave, lane);
    }
#pragma unroll
    for (int ks = 0; ks < 2; ++ks) {
      v4i a[2], b[2];
#pragma unroll
      for (int i = 0; i < 2; i++) a[i] = frag32(buf,        wm * 64 + i * 32, ks * 2, lane);
#pragma unroll
      for (int j = 0; j < 2; j++) b[j] = frag32(buf + 8192, wn * 64 + j * 32, ks * 2, lane);
#pragma unroll
      for (int i = 0; i < 2; i++)
#pragma unroll
        for (int j = 0; j < 2; j++)
          acc[i][j] = __builtin_amdgcn_mfma_i32_32x32x32_i8(a[i], b[j], acc[i][j], 0, 0, 0);
    }
    cur ^= 1;
  }

  const int lc = lane & 31;
  const int lh = lane >> 5;
#pragma unroll
  for (int i = 0; i < 2; i++) {
#pragma unroll
    for (int r = 0; r < 16; r++) {
      const int gr = m0 + wm * 64 + i * 32 + (r & 3) + 8 * (r >> 2) + 4 * lh;
      const float s2 = fmaxf(__uint_as_float(rowmax[gr]), 1e-8f) / 127.f;
#pragma unroll
      for (int j = 0; j < 2; j++) {
        const int gc = n0 + wn * 64 + j * 32 + lc;
        out[(size_t)gr * H_DIM + gc] = (float)acc[i][j][r] * s2 * s_wd[gc];
      }
    }
  }
}

// ---------------------------------------------------------------------------
// launch
// ---------------------------------------------------------------------------
extern "C" void kernel_launch(void* const* d_in, const int* in_sizes, int n_in,
                              void* d_out, int out_size, void* d_ws, size_t ws_size,
                              hipStream_t stream) {
  const int*   x_q     = (const int*)d_in[0];
  const float* x_scale = (const float*)d_in[1];
  const int*   w_gu    = (const int*)d_in[2];
  const float* s_wgu   = (const float*)d_in[3];
  const int*   w_d     = (const int*)d_in[4];
  const float* s_wd    = (const float*)d_in[5];
  float* out = (float*)d_out;

  char* ws = (char*)d_ws;
  const size_t SZ_X8   = (size_t)T_DIM * H_DIM;
  const size_t SZ_WGU8 = (size_t)2 * I_DIM * H_DIM;
  const size_t SZ_WD8  = (size_t)H_DIM * I_DIM;
  const size_t SZ_Y    = (size_t)T_DIM * I_DIM * 4;
  const size_t SZ_YQ   = (size_t)T_DIM * I_DIM;

  int8_t*   x8     = (int8_t*)ws;
  int8_t*   wgu8   = (int8_t*)(ws + SZ_X8);
  int8_t*   wd8    = (int8_t*)(ws + SZ_X8 + SZ_WGU8);
  float*    y      = (float*)(ws + SZ_X8 + SZ_WGU8 + SZ_WD8);
  int8_t*   yq8    = (int8_t*)(ws + SZ_X8 + SZ_WGU8 + SZ_WD8 + SZ_Y);
  unsigned* rowmax = (unsigned*)(ws + SZ_X8 + SZ_WGU8 + SZ_WD8 + SZ_Y + SZ_YQ);

  pack_i8<<<dim3(4096), dim3(256), 0, stream>>>((const int4*)x_q,  (v4i*)x8,   (int)(SZ_X8 / 16));
  pack_i8<<<dim3(4096), dim3(256), 0, stream>>>((const int4*)w_gu, (v4i*)wgu8, (int)(SZ_WGU8 / 16));
  pack_i8<<<dim3(4096), dim3(256), 0, stream>>>((const int4*)w_d,  (v4i*)wd8,  (int)(SZ_WD8 / 16));
  zero_u32<<<dim3(16), dim3(256), 0, stream>>>(rowmax, T_DIM);

  gemm1_silu<<<dim3(I_DIM / 128, T_DIM / 128), dim3(256), 0, stream>>>(
      x8, wgu8, x_scale, s_wgu, y, rowmax);

  quantize_y<<<dim3((unsigned)(((size_t)T_DIM * I_DIM / 16 + 255) / 256)), dim3(256), 0, stream>>>(
      y, rowmax, (v4i*)yq8);

  gemm2_scaled<<<dim3(H_DIM / 128, T_DIM / 128), dim3(256), 0, stream>>>(
      yq8, wd8, rowmax, s_wd, out);
}